// Round 5
// baseline (377.620 us; speedup 1.0000x reference)
//
#include <hip/hip_runtime.h>
#include <hip/hip_bf16.h>

#define DMODEL 1024
#define NH 16
#define DKH 64
#define NB 4
#define SEQ 2048
#define MTOT (NB*SEQ)   // 8192

typedef __bf16 bf16_t;
typedef __bf16 bf16x8 __attribute__((ext_vector_type(8)));
typedef float f32x4 __attribute__((ext_vector_type(4)));

__device__ __forceinline__ void async_copy16(void* lds, const void* g) {
    __builtin_amdgcn_global_load_lds(
        (const __attribute__((address_space(1))) unsigned int*)g,
        (__attribute__((address_space(3))) unsigned int*)lds, 16, 0, 0);
}

// native v_exp_f32: computes 2^x
__device__ __forceinline__ float fast_exp2(float x) {
    return __builtin_amdgcn_exp2f(x);
}

__device__ __forceinline__ float rsum16(float v) {
    v += __shfl_xor(v, 1);
    v += __shfl_xor(v, 2);
    v += __shfl_xor(v, 4);
    v += __shfl_xor(v, 8);
    return v;
}

// fp32 -> bf16 elementwise; blockIdx.y selects tensor.
__global__ void cvt_kernel(const float* __restrict__ s0, const float* __restrict__ s1,
                           const float* __restrict__ s2, const float* __restrict__ s3,
                           bf16_t* __restrict__ d0, bf16_t* __restrict__ d1,
                           bf16_t* __restrict__ d2, bf16_t* __restrict__ d3, int n)
{
    const float* s = (blockIdx.y == 0) ? s0 : (blockIdx.y == 1) ? s1 :
                     (blockIdx.y == 2) ? s2 : s3;
    bf16_t* d = (blockIdx.y == 0) ? d0 : (blockIdx.y == 1) ? d1 :
                (blockIdx.y == 2) ? d2 : d3;
    int i = (blockIdx.x * 256 + threadIdx.x) * 8;
    if (i < n) {
        float4 a = *(const float4*)&s[i];
        float4 b = *(const float4*)&s[i + 4];
        union { bf16_t h[8]; uint4 u; } t;
        t.h[0]=(bf16_t)a.x; t.h[1]=(bf16_t)a.y; t.h[2]=(bf16_t)a.z; t.h[3]=(bf16_t)a.w;
        t.h[4]=(bf16_t)b.x; t.h[5]=(bf16_t)b.y; t.h[6]=(bf16_t)b.z; t.h[7]=(bf16_t)b.w;
        *(uint4*)&d[i] = t.u;
    }
}

// NT GEMM, bf16, 128x128 tile, BK=64, global_load_lds 16B staging,
// m97 single-buffer 2-barrier structure (proven R2). Output projection only.
// OUT_MODE 1: fp32 row-major out[m*N + n]
template<int OUT_MODE>
__global__ __launch_bounds__(256, 3)
void gemm_bt(const bf16_t* __restrict__ A, const bf16_t* __restrict__ W,
             const float* __restrict__ bias, void* __restrict__ out,
             int M, int N, int K, float scale)
{
    __shared__ bf16_t As[128 * 64];
    __shared__ bf16_t Ws[128 * 64];

    const int tid  = threadIdx.x;
    const int wave = tid >> 6;
    const int lane = tid & 63;
    const int ln   = lane & 15;
    const int quad = lane >> 4;
    const int wm   = (wave >> 1) * 64;
    const int wn   = (wave & 1) * 64;
    const int bm   = blockIdx.x * 128;
    const int bn   = blockIdx.y * 128;
    const int srow = wave * 8 + (lane >> 3);
    const int sg   = (lane & 7) * 8;

    f32x4 acc[4][4] = {};

    for (int k0 = 0; k0 < K; k0 += 64) {
        #pragma unroll
        for (int rr = 0; rr < 4; ++rr) {
            int row = rr * 32 + srow;
            async_copy16(&As[(size_t)(rr * 32 + wave * 8) * 64],
                         &A[(size_t)(bm + row) * K + k0 + sg]);
            async_copy16(&Ws[(size_t)(rr * 32 + wave * 8) * 64],
                         &W[(size_t)(bn + row) * K + k0 + sg]);
        }
        __syncthreads();   // drains vmcnt: tile resident

        bf16x8 af[2][4], wf[2][4];
        #pragma unroll
        for (int h = 0; h < 2; ++h)
            #pragma unroll
            for (int u = 0; u < 4; ++u) {
                af[h][u] = *(const bf16x8*)&As[(wm + u * 16 + ln) * 64 + h * 32 + quad * 8];
                wf[h][u] = *(const bf16x8*)&Ws[(wn + u * 16 + ln) * 64 + h * 32 + quad * 8];
            }
        #pragma unroll
        for (int h = 0; h < 2; ++h)
            #pragma unroll
            for (int im = 0; im < 4; ++im)
                #pragma unroll
                for (int jn = 0; jn < 4; ++jn)
                    acc[im][jn] = __builtin_amdgcn_mfma_f32_16x16x32_bf16(
                        af[h][im], wf[h][jn], acc[im][jn], 0, 0, 0);

        __syncthreads();   // all reads done before next stage overwrites
    }

    #pragma unroll
    for (int jn = 0; jn < 4; ++jn) {
        int n = bn + wn + jn * 16 + ln;
        float bv = bias[n];
        #pragma unroll
        for (int im = 0; im < 4; ++im) {
            #pragma unroll
            for (int r = 0; r < 4; ++r) {
                int m = bm + wm + im * 16 + quad * 4 + r;
                float v = (acc[im][jn][r] + bv) * scale;
                ((float*)out)[(size_t)m * N + n] = v;
            }
        }
    }
}

// Fused Q/K/V projection, ROUND 5: 256x128 tile, 512 threads (8 waves as
// 4M x 2N, per-wave 64x64 out). Same proven single-buffer 2-barrier loop.
// Why: m233 says the 2-phase critical path is stage+vmcnt+barrier; bigger
// tile cuts staged-bytes-per-MFMA to 0.75x (48KB staged per 2x MFMA work)
// and staging instrs per thread 8->6. LDS 48KB -> up to 3 blocks/CU of
// 8 waves (16-24 waves/CU vs ~8). Grid (32,24)=768: exact generations.
// NEW: rule-#21 XOR swizzle on BOTH A and W staging (inverse-swizzled
// global source chunk ^= row&7, linear LDS dest, swizzled ds_read) -- the
// exact pattern proven in attn for 4 rounds. Fragment reads become
// bank-optimal (8 lanes per 4-bank group x 8 groups = minimum 8 cycles),
// killing the 18.9M conflict cycles.
// blockIdx.y>>3 selects (A, bias, out, scale, layout) block-uniformly.
// W3 = Wq|Wk|Wv packed as 3072x1024.
__global__ __launch_bounds__(512, 2)
void gemm_qkv(const bf16_t* __restrict__ Aq, const bf16_t* __restrict__ Ak,
              const bf16_t* __restrict__ Av, const bf16_t* __restrict__ W3,
              const float* __restrict__ bqp, const float* __restrict__ bkp,
              const float* __restrict__ bvp,
              bf16_t* __restrict__ Qh, bf16_t* __restrict__ Kh,
              bf16_t* __restrict__ Vth, float qscale)
{
    __shared__ __align__(16) bf16_t As[256 * 64];   // 32 KB
    __shared__ __align__(16) bf16_t Ws[128 * 64];   // 16 KB

    const int K    = DMODEL;
    const int tid  = threadIdx.x;
    const int wave = tid >> 6;
    const int lane = tid & 63;
    const int ln   = lane & 15;
    const int quad = lane >> 4;
    const int wr   = wave >> 1;          // 0..3 -> rows wr*64
    const int wc   = wave & 1;           // 0..1 -> cols wc*64
    const int cs   = ln & 7;             // read-side swizzle key (= row & 7)
    const int bm   = blockIdx.x * 256;
    const int bnG  = blockIdx.y * 128;   // 0..2943 into packed W3
    const int sel  = blockIdx.y >> 3;    // 0=Q, 1=K, 2=V (block-uniform)
    const bf16_t* A = (sel == 0) ? Aq : (sel == 1) ? Ak : Av;

    // staging assignment: thread t -> row t>>3 within a 64-row batch,
    // LDS chunk t&7 (linear); global source chunk = (t&7) ^ (row&7).
    const int srow8 = tid >> 3;          // 0..63
    const int schk  = tid & 7;

    f32x4 acc[4][4] = {};

    for (int k0 = 0; k0 < K; k0 += 64) {
        // A: 4 batches of 64 rows
        #pragma unroll
        for (int b = 0; b < 4; ++b) {
            const int row = b * 64 + srow8;
            const int csr = schk ^ (row & 7);
            async_copy16(&As[(size_t)(b * 64 + (tid >> 6) * 8) * 64],
                         &A[(size_t)(bm + row) * K + k0 + csr * 8]);
        }
        // W: 2 batches of 64 rows
        #pragma unroll
        for (int b = 0; b < 2; ++b) {
            const int row = b * 64 + srow8;
            const int csr = schk ^ (row & 7);
            async_copy16(&Ws[(size_t)(b * 64 + (tid >> 6) * 8) * 64],
                         &W3[(size_t)(bnG + row) * K + k0 + csr * 8]);
        }
        __syncthreads();   // drains vmcnt: tile resident

        bf16x8 af[2][4], wf[2][4];
        #pragma unroll
        for (int h = 0; h < 2; ++h)
            #pragma unroll
            for (int u = 0; u < 4; ++u) {
                af[h][u] = *(const bf16x8*)&As[(wr * 64 + u * 16 + ln) * 64 +
                                               ((h * 4 + quad) ^ cs) * 8];
                wf[h][u] = *(const bf16x8*)&Ws[(wc * 64 + u * 16 + ln) * 64 +
                                               ((h * 4 + quad) ^ cs) * 8];
            }
        #pragma unroll
        for (int h = 0; h < 2; ++h)
            #pragma unroll
            for (int im = 0; im < 4; ++im)
                #pragma unroll
                for (int jn = 0; jn < 4; ++jn)
                    acc[im][jn] = __builtin_amdgcn_mfma_f32_16x16x32_bf16(
                        af[h][im], wf[h][jn], acc[im][jn], 0, 0, 0);

        __syncthreads();
    }

    const float* bias = (sel == 0) ? bqp : (sel == 1) ? bkp : bvp;
    const float scale = (sel == 0) ? qscale : 1.0f;
    const int bn = bnG & (DMODEL - 1);       // col within the selected 1024

    #pragma unroll
    for (int jn = 0; jn < 4; ++jn) {
        int n = bn + wc * 64 + jn * 16 + ln;
        float bv = bias[n];
        int h = n >> 6, d = n & 63;
        #pragma unroll
        for (int im = 0; im < 4; ++im) {
            #pragma unroll
            for (int r = 0; r < 4; ++r) {
                int m = bm + wr * 64 + im * 16 + quad * 4 + r;
                float v = (acc[im][jn][r] + bv) * scale;
                int b = m >> 11, s = m & (SEQ - 1);
                if (sel == 2) {
                    Vth[(((size_t)(b * NH + h)) * DKH + d) * SEQ + s] = (bf16_t)v;
                } else {
                    bf16_t* outp = (sel == 1) ? Kh : Qh;
                    outp[(((size_t)(b * NH + h)) * SEQ + s) * DKH + d] = (bf16_t)v;
                }
            }
        }
    }
}

// Flash attention, causal, NO-MAX softmax, complementary Q-tile pairing (R4).
// ROUND 5 micro-fix: within each strip pair, SPLIT the exp+Ps-write loop
// from the Ps-read+PV loop (R4 fused them per-strip -> back-to-back
// ds_write/ds_read of the SAME rows = full LDS turnaround stall twice per
// tile; splitting fills the gap with the other strip's VALU work).
__global__ __launch_bounds__(256, 2)
void attn_kernel(const bf16_t* __restrict__ Q, const bf16_t* __restrict__ Km,
                 const bf16_t* __restrict__ Vt, bf16_t* __restrict__ X)
{
    __shared__ __align__(16) bf16_t Ks[2][64 * 64];
    __shared__ __align__(16) bf16_t Vs[2][64 * 64];
    __shared__ __align__(16) bf16_t Ps[4][32][72];

    const int tid  = threadIdx.x;
    const int wave = tid >> 6;
    const int lane = tid & 63;
    const int ln   = lane & 15;
    const int quad = lane >> 4;
    const int cs   = ln & 7;              // read-side swizzle key (= row & 7)

    const int bh  = blockIdx.x;           // bh-fast -> same XCD per bh
    const int qtA = blockIdx.y;           // 0..7
    const int qtB = 15 - qtA;
    const int q0A = qtA * 128;
    const int q0B = qtB * 128;
    const size_t base = (size_t)bh * SEQ * DKH;

    // 4 strips of 16 rows per wave: s0=q0A, s1=q0A+64, s2=q0B, s3=q0B+64
    bf16x8 aq[4][2];
    #pragma unroll
    for (int st = 0; st < 4; ++st) {
        const int sb = ((st < 2) ? q0A : q0B) + (st & 1) * 64;
        const bf16_t* qr = Q + base + (size_t)(sb + wave * 16 + ln) * DKH;
        aq[st][0] = *(const bf16x8*)(qr + quad * 8);
        aq[st][1] = *(const bf16x8*)(qr + 32 + quad * 8);
    }

    f32x4 oacc[4][4] = {};
    float psum[4][4] = {};

    const int nkt = 2 * qtB + 2;          // key tiles for the LATE Q-tile

    const int srow8 = lane >> 3;
    const int schk  = lane & 7;

    // prologue: stage tile 0 into buffer 0
    #pragma unroll
    for (int qq = 0; qq < 2; ++qq) {
        const int rb  = wave * 16 + qq * 8;
        const int row = rb + srow8;
        const int csr = schk ^ (row & 7);
        async_copy16(&Ks[0][rb * 64], Km + base + (size_t)row * DKH + csr * 8);
        async_copy16(&Vs[0][rb * 64], Vt + base + (size_t)row * SEQ + csr * 8);
    }
    __syncthreads();   // drain: buffer 0 resident

    int cur = 0;
    for (int kt = 0; kt < nkt; ++kt, cur ^= 1) {
        const int j0 = kt * 64;

        // issue next tile's staging first: in flight across the whole compute
        if (kt + 1 < nkt) {
            const int jn0 = j0 + 64;
            #pragma unroll
            for (int qq = 0; qq < 2; ++qq) {
                const int rb  = wave * 16 + qq * 8;
                const int row = rb + srow8;
                const int csr = schk ^ (row & 7);
                async_copy16(&Ks[cur ^ 1][rb * 64],
                             Km + base + (size_t)(jn0 + row) * DKH + csr * 8);
                async_copy16(&Vs[cur ^ 1][rb * 64],
                             Vt + base + (size_t)row * SEQ + jn0 + csr * 8);
            }
        }

        bf16x8 kf[4][2];
        #pragma unroll
        for (int jn = 0; jn < 4; ++jn) {
            const int rr = (jn * 16 + ln) * 64;
            kf[jn][0] = *(const bf16x8*)&Ks[cur][rr + ((quad    ) ^ cs) * 8];
            kf[jn][1] = *(const bf16x8*)&Ks[cur][rr + ((4 + quad) ^ cs) * 8];
        }
        bf16x8 vf[4][2];
        #pragma unroll
        for (int nj = 0; nj < 4; ++nj) {
            const int rr = (nj * 16 + ln) * 64;
            vf[nj][0] = *(const bf16x8*)&Vs[cur][rr + ((quad    ) ^ cs) * 8];
            vf[nj][1] = *(const bf16x8*)&Vs[cur][rr + ((4 + quad) ^ cs) * 8];
        }

        // strip pairs {0,1} (Q-tile A) and {2,3} (Q-tile B)
        #pragma unroll
        for (int pair = 0; pair < 2; ++pair) {
            const int q0p = (pair == 0) ? q0A : q0B;

            f32x4 s[2][4] = {};
            #pragma unroll
            for (int sl = 0; sl < 2; ++sl) {
                const int st = pair * 2 + sl;
                const int sb = q0p + sl * 64;
                if (j0 > sb + 63) continue;       // strip fully masked (uniform)
                #pragma unroll
                for (int jn = 0; jn < 4; ++jn) {
                    s[sl][jn] = __builtin_amdgcn_mfma_f32_16x16x32_bf16(aq[st][0], kf[jn][0], s[sl][jn], 0, 0, 0);
                    s[sl][jn] = __builtin_amdgcn_mfma_f32_16x16x32_bf16(aq[st][1], kf[jn][1], s[sl][jn], 0, 0, 0);
                }
            }

            // phase 1: mask + exp + Ps write, BOTH strips
            #pragma unroll
            for (int sl = 0; sl < 2; ++sl) {
                const int st = pair * 2 + sl;
                const int sb = q0p + sl * 64;
                if (j0 > sb + 63) continue;       // strip fully masked
                const int rbase = sb + wave * 16 + quad * 4;
                const bool diag = (j0 + 63 > sb);
                #pragma unroll
                for (int r = 0; r < 4; ++r) {
                    float rowsum = 0.f;
                    #pragma unroll
                    for (int jn = 0; jn < 4; ++jn) {
                        float v = s[sl][jn][r];
                        if (diag) {
                            int col = j0 + jn * 16 + ln;
                            if (col > rbase + r) v = -1e30f;
                        }
                        float p = fast_exp2(v);      // exp2(-1e30) == 0
                        s[sl][jn][r] = p;
                        rowsum += p;
                    }
                    psum[st][r] += rowsum;
                }
                #pragma unroll
                for (int r = 0; r < 4; ++r)
                    #pragma unroll
                    for (int jn = 0; jn < 4; ++jn)
                        Ps[wave][sl * 16 + quad * 4 + r][jn * 16 + ln] = (bf16_t)s[sl][jn][r];
            }

            // phase 2: Ps read + PV, BOTH strips (same-wave order, no barrier)
            #pragma unroll
            for (int sl = 0; sl < 2; ++sl) {
                const int st = pair * 2 + sl;
                const int sb = q0p + sl * 64;
                if (j0 > sb + 63) continue;       // strip fully masked
                bf16x8 ap0 = *(const bf16x8*)&Ps[wave][sl * 16 + ln][quad * 8];
                bf16x8 ap1 = *(const bf16x8*)&Ps[wave][sl * 16 + ln][32 + quad * 8];
                #pragma unroll
                for (int nj = 0; nj < 4; ++nj) {
                    oacc[st][nj] = __builtin_amdgcn_mfma_f32_16x16x32_bf16(ap0, vf[nj][0], oacc[st][nj], 0, 0, 0);
                    oacc[st][nj] = __builtin_amdgcn_mfma_f32_16x16x32_bf16(ap1, vf[nj][1], oacc[st][nj], 0, 0, 0);
                }
            }
        }

        // one barrier per tile: drains next-tile staging (vmcnt) and orders
        // this tile's LDS reads before buffer reuse (lgkmcnt)
        __syncthreads();
    }

    const int bb = bh >> 4, hh = bh & 15;
    #pragma unroll
    for (int st = 0; st < 4; ++st) {
        const int sb = ((st < 2) ? q0A : q0B) + (st & 1) * 64;
        #pragma unroll
        for (int r = 0; r < 4; ++r) {
            int sg = sb + wave * 16 + quad * 4 + r;
            float inv = 1.f / rsum16(psum[st][r]);
            #pragma unroll
            for (int nj = 0; nj < 4; ++nj)
                X[((size_t)(bb * SEQ + sg)) * DMODEL + hh * DKH + nj * 16 + ln] =
                    (bf16_t)(oacc[st][nj][r] * inv);
        }
    }
}

extern "C" void kernel_launch(void* const* d_in, const int* in_sizes, int n_in,
                              void* d_out, int out_size, void* d_ws, size_t ws_size,
                              hipStream_t stream)
{
    const float* query = (const float*)d_in[0];
    const float* key   = (const float*)d_in[1];
    const float* value = (const float*)d_in[2];
    const float* Wq = (const float*)d_in[4];
    const float* bq = (const float*)d_in[5];
    const float* Wk = (const float*)d_in[6];
    const float* bk = (const float*)d_in[7];
    const float* Wv = (const float*)d_in[8];
    const float* bv = (const float*)d_in[9];
    const float* Wo = (const float*)d_in[10];
    const float* bo = (const float*)d_in[11];
    float* out = (float*)d_out;

    // Buffer plan (ws 72 MB + d_out 32 MB used as scratch), as R2:
    //  ws[0,16)   qb   (bf16 query)        -> X after attn (qb dead then)
    //  ws[16,32)  kb   (bf16 key)
    //  ws[32,48)  vb   (bf16 value)
    //  ws[48,64)  Qh
    //  ws[64,70)  Wqb|Wkb|Wvb  (contiguous 3072x1024 packed W3)
    //  ws[70,72)  Wob
    //  d_out[0,16)  Kh   (scratch; dead before gemmO writes out)
    //  d_out[16,32) Vth  (scratch; dead before gemmO writes out)
    char* ws = (char*)d_ws;
    bf16_t* qb  = (bf16_t*)(ws);
    bf16_t* kb  = (bf16_t*)(ws + ((size_t)16 << 20));
    bf16_t* vb  = (bf16_t*)(ws + ((size_t)32 << 20));
    bf16_t* Qh  = (bf16_t*)(ws + ((size_t)48 << 20));
    bf16_t* Wqb = (bf16_t*)(ws + ((size_t)64 << 20));
    bf16_t* Wkb = (bf16_t*)(ws + ((size_t)66 << 20));
    bf16_t* Wvb = (bf16_t*)(ws + ((size_t)68 << 20));
    bf16_t* Wob = (bf16_t*)(ws + ((size_t)70 << 20));
    bf16_t* Kh  = (bf16_t*)d_out;
    bf16_t* Vth = (bf16_t*)((char*)d_out + ((size_t)16 << 20));
    bf16_t* X   = qb;

    const int nAct = MTOT * DMODEL;
    const int nW   = DMODEL * DMODEL;
    cvt_kernel<<<dim3(nAct / 2048, 3), 256, 0, stream>>>(query, key, value, query,
                                                         qb, kb, vb, qb, nAct);
    cvt_kernel<<<dim3(nW / 2048, 4), 256, 0, stream>>>(Wq, Wk, Wv, Wo,
                                                       Wqb, Wkb, Wvb, Wob, nW);

    const float qscale = 0.125f * 1.4426950408889634f;  // 1/sqrt(dk) * log2(e)

    // 256x128 tile: grid (8192/256, 3072/128) = (32, 24), 512 threads
    gemm_qkv<<<dim3(MTOT / 256, 3 * DMODEL / 128), dim3(512), 0, stream>>>(
        qb, kb, vb, Wqb, bq, bk, bv, Qh, Kh, Vth, qscale);

    // bh-fast grid: 64 x 8 (complementary Q-tile pairing inside)
    attn_kernel<<<dim3(NB * NH, SEQ / 256), dim3(256), 0, stream>>>(Qh, Kh, Vth, X);

    gemm_bt<1><<<dim3(MTOT / 128, DMODEL / 128), dim3(256), 0, stream>>>(
        X, Wob, bo, out, MTOT, DMODEL, DMODEL, 1.0f);
}